// Round 5
// baseline (408.271 us; speedup 1.0000x reference)
//
#include <hip/hip_runtime.h>

#define EPS 1e-5f
#define WAVES 4

typedef __attribute__((ext_vector_type(8)))  short short8;
typedef __attribute__((ext_vector_type(4)))  short short4_t;
typedef __attribute__((ext_vector_type(4)))  float f32x4;
typedef __attribute__((ext_vector_type(2)))  float f32x2;

__device__ inline unsigned f2bf(float f) {
    unsigned u = __builtin_bit_cast(unsigned, f);
    return (u + 0x7fffu + ((u >> 16) & 1u)) >> 16;   // RNE f32->bf16
}

// One prep kernel, three regions of d_ws:
//  [0)        w2f:  w2 bf16 in mfma_f32_16x16x32_bf16 B-frag order
//             w2f[((nf*8+ks)*64+lane)*8+e] = bf16(w2[ks*32+(lane>>4)*8+e][nf*16+(lane&15)])
//  [131072)   emb2: emb + b2 broadcast (folds b2 out of the epilogue)
//  [233472)   gb:   interleaved {gamma,beta} pairs
__global__ void prep(const float* __restrict__ w2, const float* __restrict__ emb,
                     const float* __restrict__ b2, const float* __restrict__ gamma,
                     const float* __restrict__ beta,
                     unsigned short* __restrict__ w2f, float* __restrict__ emb2,
                     float* __restrict__ gb) {
    int idx = blockIdx.x * 256 + threadIdx.x;
    if (idx < 65536) {
        int e    = idx & 7;
        int lane = (idx >> 3) & 63;
        int ks   = (idx >> 9) & 7;
        int nf   = idx >> 12;
        int k    = ks * 32 + ((lane >> 4) << 3) + e;
        int n    = nf * 16 + (lane & 15);
        w2f[idx] = (unsigned short)f2bf(w2[k * 256 + n]);
    } else if (idx < 65536 + 25600) {
        int i = idx - 65536;
        emb2[i] = emb[i] + b2[i & 255];
    } else if (idx < 65536 + 25600 + 256) {
        int c = idx - (65536 + 25600);
        gb[c * 2]     = gamma[c];
        gb[c * 2 + 1] = beta[c];
    }
}

__global__ __launch_bounds__(256, 4) void fused_kernel(
    const int* __restrict__ z, const float* __restrict__ x,
    const float* __restrict__ w1, const float* __restrict__ b1,
    const unsigned short* __restrict__ w2f, const float* __restrict__ emb2,
    const float* __restrict__ gb, float* __restrict__ out, int N)
{
    // All LDS PER-WAVE: no __syncthreads (within-wave producer/consumer; DS pipe
    // is in-order per wave). 16-row tiles -> 8KB/wave A-tile -> 4 blocks/CU.
    __shared__ char  p_lds[WAVES * 8192];    // per-wave 16x256 bf16 A-tile (swizzled)
    __shared__ float x_lds[WAVES][16][3];
    __shared__ int   z_lds[WAVES][16];

    const int tid  = threadIdx.x;
    const int wave = tid >> 6;
    const int lane = tid & 63;
    const int l15  = lane & 15;
    const int h4   = lane >> 4;
    char* pbuf = p_lds + wave * 8192;

    const int tiles = N >> 4;
    const int t = blockIdx.x * WAVES + wave;
    if (t >= tiles) return;                  // per-wave exit legal: no barriers
    const int R = t << 4;

    if (lane < 16) {
        int r = R + lane;
        x_lds[wave][lane][0] = x[r * 3 + 0];
        x_lds[wave][lane][1] = x[r * 3 + 1];
        x_lds[wave][lane][2] = x[r * 3 + 2];
        z_lds[wave][lane]    = z[r];
    }

    // ---- init acc with emb2 gather (C/D layout: col=lane&15, row=(lane>>4)*4+j);
    // the 64 L2-hit loads fly while the silu chain below executes.
    f32x4 acc[16];
#pragma unroll
    for (int j = 0; j < 4; ++j) {
        const int rl = h4 * 4 + j;
        const float* er = emb2 + (size_t)z_lds[wave][rl] * 256 + l15;
#pragma unroll
        for (int nf = 0; nf < 16; ++nf)
            acc[nf][j] = er[nf * 16];
    }

    // hoisted per-lane weights: this lane computes p columns [lane*4, lane*4+3]
    const int  c0  = lane * 4;
    const f32x4 w1a = *(const f32x4*)(w1 + c0);
    const f32x4 w1b = *(const f32x4*)(w1 + 256 + c0);
    const f32x4 w1c = *(const f32x4*)(w1 + 512 + c0);
    const f32x4 b1v = *(const f32x4*)(b1 + c0);

    // p = silu(x @ w1 + b1) -> bf16 LDS tile, XOR-swizzled rows
#pragma unroll
    for (int r = 0; r < 16; ++r) {
        float x0 = x_lds[wave][r][0];
        float x1 = x_lds[wave][r][1];
        float x2 = x_lds[wave][r][2];
        short4_t pv;
#pragma unroll
        for (int j = 0; j < 4; ++j) {
            float tv = x0 * w1a[j] + x1 * w1b[j] + x2 * w1c[j] + b1v[j];
            float s  = tv * __builtin_amdgcn_rcpf(1.f + __expf(-tv));
            pv[j] = (short)f2bf(s);
        }
        int off = (r * 512 + lane * 8) ^ ((r & 7) << 4);
        *(short4_t*)(pbuf + off) = pv;
    }

    // GEMM: [16,256] @ [256,256] via mfma_f32_16x16x32_bf16 (acc pre-loaded w/ emb2)
    // A-frag: row=lane&15, k=ks*32+(lane>>4)*8+e
#pragma unroll
    for (int ks = 0; ks < 8; ++ks) {
        int aoff = (l15 * 512 + ks * 64 + h4 * 16) ^ ((l15 & 7) << 4);
        short8 a = *(const short8*)(pbuf + aoff);
        const unsigned short* bp = w2f + ks * 512 + lane * 8;
#pragma unroll
        for (int nf = 0; nf < 16; ++nf) {
            short8 b = *(const short8*)(bp + nf * 4096);
            acc[nf] = __builtin_amdgcn_mfma_f32_16x16x32_bf16(a, b, acc[nf], 0, 0, 0);
        }
    }

    // epilogue: LayerNorm (row lives in one 16-lane group) ; NT stores (no L2
    // write-allocate RFO).
#pragma unroll
    for (int j = 0; j < 4; ++j) {
        const int rl = h4 * 4 + j;
        float hv[16];
        float hsum = 0.f, hsq = 0.f;
#pragma unroll
        for (int nf = 0; nf < 16; ++nf) {
            float v = acc[nf][j];
            hv[nf] = v; hsum += v; hsq += v * v;
        }
#pragma unroll
        for (int d = 1; d < 16; d <<= 1) {
            hsum += __shfl_xor(hsum, d, 64);
            hsq  += __shfl_xor(hsq,  d, 64);
        }
        float mu  = hsum * (1.f / 256.f);
        float var = hsq * (1.f / 256.f) - mu * mu;
        float rs  = rsqrtf(var + EPS);
        float* orow = out + (size_t)(R + rl) * 256 + l15;
#pragma unroll
        for (int nf = 0; nf < 16; ++nf) {
            f32x2 g = *(const f32x2*)(gb + (nf * 16 + l15) * 2);
            __builtin_nontemporal_store((hv[nf] - mu) * rs * g[0] + g[1],
                                        orow + nf * 16);
        }
    }
}

extern "C" void kernel_launch(void* const* d_in, const int* in_sizes, int n_in,
                              void* d_out, int out_size, void* d_ws, size_t ws_size,
                              hipStream_t stream) {
    const int*   z     = (const int*)d_in[0];
    const float* x     = (const float*)d_in[1];
    const float* emb   = (const float*)d_in[2];
    const float* w1    = (const float*)d_in[3];
    const float* b1    = (const float*)d_in[4];
    const float* w2    = (const float*)d_in[5];
    const float* b2    = (const float*)d_in[6];
    const float* gamma = (const float*)d_in[7];
    const float* beta  = (const float*)d_in[8];
    float* out = (float*)d_out;
    const int N = in_sizes[0];

    unsigned short* w2f  = (unsigned short*)d_ws;                  // 128 KB
    float*          emb2 = (float*)((char*)d_ws + 131072);        // 100 KB
    float*          gbt  = (float*)((char*)d_ws + 233472);        // 2 KB

    prep<<<(65536 + 25600 + 256 + 255) / 256, 256, 0, stream>>>(
        w2, emb, b2, gamma, beta, w2f, emb2, gbt);

    int tiles  = N >> 4;                       // 16-row tiles, one per wave
    int blocks = (tiles + WAVES - 1) / WAVES;
    fused_kernel<<<blocks, 256, 0, stream>>>(z, x, w1, b1, w2f, emb2, gbt, out, N);
}